// Round 3
// baseline (322.195 us; speedup 1.0000x reference)
//
#include <hip/hip_runtime.h>

#define B_  512
#define T_  512
#define V_  96
#define H_  128
#define TPB 128          // 2 waves per block; 1 block = 1 batch row
#define HP  160          // padded h state: 4 chunks * 40 floats
#define CHK 40           // chunk stride (32 data + 8 pad) -> g-disjoint banks
#define WPAD 132         // wihT row stride (16B-aligned, 4-bank rotation)

// Pass 1: recover the one-hot index per (b,t). x is exactly {0.0, 1.0}.
__global__ __launch_bounds__(256) void onehot_idx_kernel(
    const float4* __restrict__ x4, int n4, int* __restrict__ idx)
{
    int stride = gridDim.x * blockDim.x;
    for (int e4 = blockIdx.x * blockDim.x + threadIdx.x; e4 < n4; e4 += stride) {
        float4 v = x4[e4];
        int base = e4 * 4;
        if (v.x > 0.5f) idx[(base + 0) / V_] = (base + 0) % V_;
        if (v.y > 0.5f) idx[(base + 1) / V_] = (base + 1) % V_;
        if (v.z > 0.5f) idx[(base + 2) / V_] = (base + 2) % V_;
        if (v.w > 0.5f) idx[(base + 3) / V_] = (base + 3) % V_;
    }
}

// a += quad-permuted a (pure-VALU cross-lane, no DS pipe)
template<int CTRL>
__device__ __forceinline__ float dpp_add(float x) {
    int y = __builtin_amdgcn_update_dpp(0, __float_as_int(x), CTRL, 0xF, 0xF, true);
    return x + __int_as_float(y);
}

__device__ __forceinline__ float fast_tanh(float s) {
    float e2 = __expf(2.0f * s);                       // v_mul + v_exp
    return 1.0f - 2.0f * __builtin_amdgcn_rcpf(e2 + 1.0f); // v_add + v_rcp + v_fma
}

// One block per batch row. Thread = (u0..u0+3 units) x (32-float K-chunk g).
// W_hh 4x32 in registers (128 VGPR); h read once, reused 4x (16 FMA per b128).
// Cross-g reduce via DPP quad_perm: zero DS ops.
__global__ __launch_bounds__(TPB, 1) void rnn_kernel(
    const float* __restrict__ W_ih, const float* __restrict__ b_ih,
    const float* __restrict__ W_hh, const float* __restrict__ b_hh,
    const float* __restrict__ W_fc, const float* __restrict__ b_fc,
    const int* __restrict__ idx, float* __restrict__ out)
{
    const int b    = blockIdx.x;
    const int tid  = threadIdx.x;
    const int wave = tid >> 6;
    const int lane = tid & 63;
    const int g    = lane & 3;              // K-chunk: floats [g*32, g*32+32)
    const int ug   = lane >> 2;             // 0..15
    const int u0   = wave * 64 + ug * 4;    // first of this thread's 4 units

    __shared__ float wihT[V_][WPAD];        // ~50.7 KiB transposed W_ih
    __shared__ float hbuf[2 * HP];          // double-buffered padded h
    __shared__ int   idx_s[T_];

    for (int e = tid; e < V_ * H_; e += TPB) {
        int hh = e / V_;
        int vv = e - hh * V_;
        wihT[vv][hh] = W_ih[e];
    }
    for (int e = tid; e < T_; e += TPB) idx_s[e] = idx[b * T_ + e];
    for (int e = tid; e < 2 * HP; e += TPB) hbuf[e] = 0.0f;

    // Register weights: W_hh[u0+m][g*32 .. g*32+31]
    float4 w[4][8];
    #pragma unroll
    for (int m = 0; m < 4; ++m) {
        const float4* p = (const float4*)(W_hh + (u0 + m) * H_ + g * 32);
        #pragma unroll
        for (int k = 0; k < 8; ++k) w[m][k] = p[k];
    }
    float4 bi = *(const float4*)(b_ih + u0);
    float4 bh = *(const float4*)(b_hh + u0);
    const float4 bias = make_float4(bi.x + bh.x, bi.y + bh.y,
                                    bi.z + bh.z, bi.w + bh.w);
    int cur = 0;
    __syncthreads();

    for (int t = 0; t < T_; ++t) {
        const int id = idx_s[t];                               // broadcast
        const float4* hc = (const float4*)(hbuf + cur * HP + g * CHK);
        float p0=0.f,q0=0.f,p1=0.f,q1=0.f,p2=0.f,q2=0.f,p3=0.f,q3=0.f;
        #pragma unroll
        for (int k = 0; k < 8; ++k) {                          // 8 b128, bank-disjoint over g
            float4 h4 = hc[k];
            p0 = fmaf(h4.x, w[0][k].x, p0); q0 = fmaf(h4.y, w[0][k].y, q0);
            p0 = fmaf(h4.z, w[0][k].z, p0); q0 = fmaf(h4.w, w[0][k].w, q0);
            p1 = fmaf(h4.x, w[1][k].x, p1); q1 = fmaf(h4.y, w[1][k].y, q1);
            p1 = fmaf(h4.z, w[1][k].z, p1); q1 = fmaf(h4.w, w[1][k].w, q1);
            p2 = fmaf(h4.x, w[2][k].x, p2); q2 = fmaf(h4.y, w[2][k].y, q2);
            p2 = fmaf(h4.z, w[2][k].z, p2); q2 = fmaf(h4.w, w[2][k].w, q2);
            p3 = fmaf(h4.x, w[3][k].x, p3); q3 = fmaf(h4.y, w[3][k].y, q3);
            p3 = fmaf(h4.z, w[3][k].z, p3); q3 = fmaf(h4.w, w[3][k].w, q3);
        }
        float a0 = p0 + q0, a1 = p1 + q1, a2 = p2 + q2, a3 = p3 + q3;
        a0 = dpp_add<0xB1>(a0); a0 = dpp_add<0x4E>(a0);        // quad butterfly
        a1 = dpp_add<0xB1>(a1); a1 = dpp_add<0x4E>(a1);
        a2 = dpp_add<0xB1>(a2); a2 = dpp_add<0x4E>(a2);
        a3 = dpp_add<0xB1>(a3); a3 = dpp_add<0x4E>(a3);
        const float4 xw = *(const float4*)&wihT[id][u0];       // input proj gather
        float h0 = fast_tanh(a0 + bias.x + xw.x);
        float h1 = fast_tanh(a1 + bias.y + xw.y);
        float h2 = fast_tanh(a2 + bias.z + xw.z);
        float h3 = fast_tanh(a3 + bias.w + xw.w);
        if (g == 0) {                                          // one writer per quad
            *(float4*)(hbuf + (cur ^ 1) * HP + (u0 >> 5) * CHK + (u0 & 31)) =
                make_float4(h0, h1, h2, h3);
        }
        cur ^= 1;
        __syncthreads();                                       // one barrier per step
    }

    // fc on final hidden state
    if (tid < V_) {
        float acc = b_fc[tid];
        const float*  hf = hbuf + cur * HP;
        const float4* wf = (const float4*)(W_fc + tid * H_);
        #pragma unroll
        for (int c = 0; c < 4; ++c) {
            #pragma unroll
            for (int k = 0; k < 8; ++k) {
                float4 h4 = ((const float4*)(hf + c * CHK))[k];
                float4 w4 = wf[c * 8 + k];
                acc = fmaf(h4.x, w4.x, acc); acc = fmaf(h4.y, w4.y, acc);
                acc = fmaf(h4.z, w4.z, acc); acc = fmaf(h4.w, w4.w, acc);
            }
        }
        out[b * V_ + tid] = acc;
    }
}

extern "C" void kernel_launch(void* const* d_in, const int* in_sizes, int n_in,
                              void* d_out, int out_size, void* d_ws, size_t ws_size,
                              hipStream_t stream)
{
    const float* x    = (const float*)d_in[0];
    const float* W_ih = (const float*)d_in[1];
    const float* b_ih = (const float*)d_in[2];
    const float* W_hh = (const float*)d_in[3];
    const float* b_hh = (const float*)d_in[4];
    const float* W_fc = (const float*)d_in[5];
    const float* b_fc = (const float*)d_in[6];
    float* out = (float*)d_out;
    int*   idx = (int*)d_ws;  // B_*T_ ints = 1 MiB scratch

    const int n4 = (B_ * T_ * V_) / 4;
    hipLaunchKernelGGL(onehot_idx_kernel, dim3(2048), dim3(256), 0, stream,
                       (const float4*)x, n4, idx);
    hipLaunchKernelGGL(rnn_kernel, dim3(B_), dim3(TPB), 0, stream,
                       W_ih, b_ih, W_hh, b_hh, W_fc, b_fc, idx, out);
}

// Round 4
// 306.092 us; speedup vs baseline: 1.0526x; 1.0526x over previous
//
#include <hip/hip_runtime.h>

#define B_  512
#define T_  512
#define V_  96
#define H_  128
#define TPB 256
#define CS  20            // chunk stride in floats (16 data + 4 pad) -> banks 20g%32 all distinct
#define NCH 8
#define HP  (NCH * CS)    // 160 floats per h buffer

#define K2F 2.8853900817779268f   // 2*log2(e): exp(2s) == exp2(K2F*s)

// Pass 1a: recover the one-hot index per (b,t). x is exactly {0.0, 1.0}.
__global__ __launch_bounds__(256) void onehot_idx_kernel(
    const float4* __restrict__ x4, int n4, int* __restrict__ idx)
{
    int stride = gridDim.x * blockDim.x;
    for (int e4 = blockIdx.x * blockDim.x + threadIdx.x; e4 < n4; e4 += stride) {
        float4 v = x4[e4];
        int base = e4 * 4;
        if (v.x > 0.5f) idx[(base + 0) / V_] = (base + 0) % V_;
        if (v.y > 0.5f) idx[(base + 1) / V_] = (base + 1) % V_;
        if (v.z > 0.5f) idx[(base + 2) / V_] = (base + 2) % V_;
        if (v.w > 0.5f) idx[(base + 3) / V_] = (base + 3) % V_;
    }
}

// Pass 1b: xwT[v][h] = (W_ih[h][v] + b_ih[h] + b_hh[h]) * 2*log2(e).
// Bias-folded + pre-scaled so the step does: exp2(fma(a, K2F, xwT_val)).
__global__ __launch_bounds__(256) void build_xwT_kernel(
    const float* __restrict__ W_ih, const float* __restrict__ b_ih,
    const float* __restrict__ b_hh, float* __restrict__ xwT)
{
    int e = blockIdx.x * blockDim.x + threadIdx.x;
    if (e < V_ * H_) {
        int v = e >> 7, h = e & 127;
        xwT[e] = (W_ih[h * V_ + v] + b_ih[h] + b_hh[h]) * K2F;
    }
}

// x + dpp_permuted(x): pure-VALU cross-lane add (no DS pipe).
template<int CTRL>
__device__ __forceinline__ float dpp_add(float x) {
    int y = __builtin_amdgcn_update_dpp(0, __float_as_int(x), CTRL, 0xF, 0xF, true);
    return x + __int_as_float(y);
}

// Pass 2: one block per batch row, 256 threads (4 waves).
// Thread = (4 units, 16-float K-chunk): lane bits {0,1,2} = chunk g,
// bits {3,4,5}+wave = unit group. 64 weight VGPRs; K-reduce = 3 DPP adds
// (xor1, xor2, xor4-via-row_half_mirror). Input-proj gather prefetched
// from global (L1) one step ahead -- zero DS gather traffic.
__global__ __launch_bounds__(TPB, 4) void rnn_kernel(
    const float* __restrict__ W_hh,
    const float* __restrict__ W_fc, const float* __restrict__ b_fc,
    const int* __restrict__ idx, const float* __restrict__ xwT,
    float* __restrict__ out)
{
    const int b    = blockIdx.x;
    const int tid  = threadIdx.x;
    const int wave = tid >> 6;
    const int lane = tid & 63;
    const int g    = lane & 7;               // K-chunk: floats [g*16, g*16+16)
    const int ug   = lane >> 3;              // 0..7
    const int u0   = wave * 32 + ug * 4;     // first of this thread's 4 units

    __shared__ float hbuf[2 * HP];           // double-buffered padded h (1.25 KiB)
    __shared__ int   idx_s[T_ + 8];

    for (int e = tid; e < T_; e += TPB) idx_s[e] = idx[b * T_ + e];
    if (tid < 8) idx_s[T_ + tid] = 0;        // pad for t+1 prefetch at t=T-1
    for (int e = tid; e < 2 * HP; e += TPB) hbuf[e] = 0.0f;

    // Weights: W_hh[u0+m][g*16 .. g*16+15] -> 16 float4 (64 VGPR)
    float4 w[4][4];
    #pragma unroll
    for (int m = 0; m < 4; ++m) {
        const float4* p = (const float4*)(W_hh + (u0 + m) * H_ + g * 16);
        #pragma unroll
        for (int k = 0; k < 4; ++k) w[m][k] = p[k];
    }
    __syncthreads();

    float4 xw = *(const float4*)(xwT + idx_s[0] * H_ + u0);
    int cur = 0;

    for (int t = 0; t < T_; ++t) {
        // prefetch next step's gather (global, L1-resident, hidden under compute)
        const float4 nxw = *(const float4*)(xwT + idx_s[t + 1] * H_ + u0);

        const float4* hc4 = (const float4*)(hbuf + cur * HP + g * CS);
        float4 ha = hc4[0], hb = hc4[1], hcv = hc4[2], hd = hc4[3];

        float a[4];
        #pragma unroll
        for (int m = 0; m < 4; ++m) {
            float p = 0.f, q = 0.f;
            p = fmaf(ha.x,  w[m][0].x, p); q = fmaf(ha.y,  w[m][0].y, q);
            p = fmaf(ha.z,  w[m][0].z, p); q = fmaf(ha.w,  w[m][0].w, q);
            p = fmaf(hb.x,  w[m][1].x, p); q = fmaf(hb.y,  w[m][1].y, q);
            p = fmaf(hb.z,  w[m][1].z, p); q = fmaf(hb.w,  w[m][1].w, q);
            p = fmaf(hcv.x, w[m][2].x, p); q = fmaf(hcv.y, w[m][2].y, q);
            p = fmaf(hcv.z, w[m][2].z, p); q = fmaf(hcv.w, w[m][2].w, q);
            p = fmaf(hd.x,  w[m][3].x, p); q = fmaf(hd.y,  w[m][3].y, q);
            p = fmaf(hd.z,  w[m][3].z, p); q = fmaf(hd.w,  w[m][3].w, q);
            float s = p + q;
            s = dpp_add<0xB1>(s);    // + chunk g^1
            s = dpp_add<0x4E>(s);    // + chunk g^2
            s = dpp_add<0x141>(s);   // + chunk g^4 (row_half_mirror; quad-uniform)
            a[m] = s;
        }
        // tanh(s) = 1 - 2/(exp2(K2F*s_total) + 1); xw is pre-scaled by K2F
        float e0 = exp2f(fmaf(a[0], K2F, xw.x));
        float e1 = exp2f(fmaf(a[1], K2F, xw.y));
        float e2 = exp2f(fmaf(a[2], K2F, xw.z));
        float e3 = exp2f(fmaf(a[3], K2F, xw.w));
        float h0 = 1.0f - 2.0f * __builtin_amdgcn_rcpf(e0 + 1.0f);
        float h1 = 1.0f - 2.0f * __builtin_amdgcn_rcpf(e1 + 1.0f);
        float h2 = 1.0f - 2.0f * __builtin_amdgcn_rcpf(e2 + 1.0f);
        float h3 = 1.0f - 2.0f * __builtin_amdgcn_rcpf(e3 + 1.0f);

        if (g == 0) {   // one writer per unit quad; chunk-strided padded layout
            *(float4*)(hbuf + (cur ^ 1) * HP + (u0 >> 4) * CS + (u0 & 15)) =
                make_float4(h0, h1, h2, h3);
        }
        cur ^= 1;
        __syncthreads();
        xw = nxw;
    }

    // fc on final hidden state
    if (tid < V_) {
        float acc = b_fc[tid];
        const float*  hf = hbuf + cur * HP;
        const float4* wf = (const float4*)(W_fc + tid * H_);
        #pragma unroll
        for (int c = 0; c < NCH; ++c) {
            #pragma unroll
            for (int k = 0; k < 4; ++k) {
                float4 h4 = *(const float4*)(hf + c * CS + 4 * k);
                float4 w4 = wf[c * 4 + k];
                acc = fmaf(h4.x, w4.x, acc); acc = fmaf(h4.y, w4.y, acc);
                acc = fmaf(h4.z, w4.z, acc); acc = fmaf(h4.w, w4.w, acc);
            }
        }
        out[b * V_ + tid] = acc;
    }
}

extern "C" void kernel_launch(void* const* d_in, const int* in_sizes, int n_in,
                              void* d_out, int out_size, void* d_ws, size_t ws_size,
                              hipStream_t stream)
{
    const float* x    = (const float*)d_in[0];
    const float* W_ih = (const float*)d_in[1];
    const float* b_ih = (const float*)d_in[2];
    const float* W_hh = (const float*)d_in[3];
    const float* b_hh = (const float*)d_in[4];
    const float* W_fc = (const float*)d_in[5];
    const float* b_fc = (const float*)d_in[6];
    float* out = (float*)d_out;

    int*   idx = (int*)d_ws;                                   // 1 MiB
    float* xwT = (float*)((char*)d_ws + (size_t)B_ * T_ * 4);  // 48 KiB

    const int n4 = (B_ * T_ * V_) / 4;
    hipLaunchKernelGGL(onehot_idx_kernel, dim3(2048), dim3(256), 0, stream,
                       (const float4*)x, n4, idx);
    hipLaunchKernelGGL(build_xwT_kernel, dim3((V_ * H_ + 255) / 256), dim3(256),
                       0, stream, W_ih, b_ih, b_hh, xwT);
    hipLaunchKernelGGL(rnn_kernel, dim3(B_), dim3(TPB), 0, stream,
                       W_hh, W_fc, b_fc, idx, xwT, out);
}

// Round 5
// 274.935 us; speedup vs baseline: 1.1719x; 1.1133x over previous
//
#include <hip/hip_runtime.h>

#define B_   512
#define T_   512
#define V_   96
#define H_   128
#define TPB  256
#define CS   20           // h chunk stride (16 data + 4 pad): banks 20g%32 distinct
#define NCH  8
#define HP   (NCH * CS)   // 160 floats per h buffer
#define WPAD 132          // wihT row stride: 132%32=4 -> gather spans all 32 banks

#define K2F 2.8853900817779268f   // 2*log2(e): exp(2s) == exp2(K2F*s)

// Pass 1: recover the one-hot index per (b,t). x is exactly {0.0, 1.0}.
__global__ __launch_bounds__(256) void onehot_idx_kernel(
    const float4* __restrict__ x4, int n4, int* __restrict__ idx)
{
    int stride = gridDim.x * blockDim.x;
    for (int e4 = blockIdx.x * blockDim.x + threadIdx.x; e4 < n4; e4 += stride) {
        float4 v = x4[e4];
        int base = e4 * 4;
        if (v.x > 0.5f) idx[(base + 0) / V_] = (base + 0) % V_;
        if (v.y > 0.5f) idx[(base + 1) / V_] = (base + 1) % V_;
        if (v.z > 0.5f) idx[(base + 2) / V_] = (base + 2) % V_;
        if (v.w > 0.5f) idx[(base + 3) / V_] = (base + 3) % V_;
    }
}

// x + dpp_permuted(x): pure-VALU cross-lane add (no DS pipe).
template<int CTRL>
__device__ __forceinline__ float dpp_add(float x) {
    int y = __builtin_amdgcn_update_dpp(0, __float_as_int(x), CTRL, 0xF, 0xF, true);
    return x + __int_as_float(y);
}

// Pass 2: one block per batch row, 256 threads (4 waves), 2 blocks/CU.
// Thread = (4 units, 16-float K-chunk). NO global loads inside the step loop:
// the barrier's vmcnt(0) drain would expose L2 latency every step. The input
// projection is gathered from an LDS table (bias-folded, pre-scaled by K2F,
// transposed, padded) staged once per block.
__global__ __launch_bounds__(TPB, 4) void rnn_kernel(
    const float* __restrict__ W_ih, const float* __restrict__ b_ih,
    const float* __restrict__ W_hh, const float* __restrict__ b_hh,
    const float* __restrict__ W_fc, const float* __restrict__ b_fc,
    const int* __restrict__ idx, float* __restrict__ out)
{
    const int b    = blockIdx.x;
    const int tid  = threadIdx.x;
    const int wave = tid >> 6;
    const int lane = tid & 63;
    const int g    = lane & 7;               // K-chunk: floats [g*16, g*16+16)
    const int ug   = lane >> 3;              // 0..7
    const int u0   = wave * 32 + ug * 4;     // first of this thread's 4 units

    __shared__ float wihT[V_][WPAD];         // ~50.7 KiB folded+scaled gather table
    __shared__ float hbuf[2 * HP];           // double-buffered padded h
    __shared__ int   idx_s[T_];

    // Stage wihT[v][h] = (W_ih[h][v] + b_ih[h] + b_hh[h]) * K2F.
    // Coalesced global read; b_ih/b_hh reads are near-uniform (L1 broadcast).
    for (int e = tid; e < V_ * H_; e += TPB) {
        int hh = e >> 6;                     // e/64? no: H index = e / V_
        hh = e / V_;
        int vv = e - hh * V_;
        wihT[vv][hh] = (W_ih[e] + b_ih[hh] + b_hh[hh]) * K2F;
    }
    for (int e = tid; e < T_; e += TPB) idx_s[e] = idx[b * T_ + e];
    for (int e = tid; e < 2 * HP; e += TPB) hbuf[e] = 0.0f;

    // Weights: W_hh[u0+m][g*16 .. g*16+15] -> 16 float4 (64 VGPR)
    float4 w[4][4];
    #pragma unroll
    for (int m = 0; m < 4; ++m) {
        const float4* p = (const float4*)(W_hh + (u0 + m) * H_ + g * 16);
        #pragma unroll
        for (int k = 0; k < 4; ++k) w[m][k] = p[k];
    }
    __syncthreads();

    int cur = 0;
    for (int t = 0; t < T_; ++t) {
        const int id = idx_s[t];                               // LDS broadcast
        // gather early (8 bcast addrs/wave, all 32 banks once): used after reduce
        const float4 xw = *(const float4*)&wihT[id][u0];

        const float4* hc4 = (const float4*)(hbuf + cur * HP + g * CS);
        float4 ha = hc4[0], hb = hc4[1], hcv = hc4[2], hd = hc4[3];

        float a[4];
        #pragma unroll
        for (int m = 0; m < 4; ++m) {
            float p = 0.f, q = 0.f;
            p = fmaf(ha.x,  w[m][0].x, p); q = fmaf(ha.y,  w[m][0].y, q);
            p = fmaf(ha.z,  w[m][0].z, p); q = fmaf(ha.w,  w[m][0].w, q);
            p = fmaf(hb.x,  w[m][1].x, p); q = fmaf(hb.y,  w[m][1].y, q);
            p = fmaf(hb.z,  w[m][1].z, p); q = fmaf(hb.w,  w[m][1].w, q);
            p = fmaf(hcv.x, w[m][2].x, p); q = fmaf(hcv.y, w[m][2].y, q);
            p = fmaf(hcv.z, w[m][2].z, p); q = fmaf(hcv.w, w[m][2].w, q);
            p = fmaf(hd.x,  w[m][3].x, p); q = fmaf(hd.y,  w[m][3].y, q);
            p = fmaf(hd.z,  w[m][3].z, p); q = fmaf(hd.w,  w[m][3].w, q);
            float s = p + q;
            s = dpp_add<0xB1>(s);    // + chunk g^1 (quad_perm)
            s = dpp_add<0x4E>(s);    // + chunk g^2 (quad_perm)
            s = dpp_add<0x141>(s);   // + chunk g^4 (row_half_mirror; quad-uniform)
            a[m] = s;
        }
        // tanh(s) = 1 - 2/(exp2(K2F*s + xw) + 1); xw pre-scaled & bias-folded
        float e0 = __builtin_amdgcn_exp2f(fmaf(a[0], K2F, xw.x));
        float e1 = __builtin_amdgcn_exp2f(fmaf(a[1], K2F, xw.y));
        float e2 = __builtin_amdgcn_exp2f(fmaf(a[2], K2F, xw.z));
        float e3 = __builtin_amdgcn_exp2f(fmaf(a[3], K2F, xw.w));
        float h0 = 1.0f - 2.0f * __builtin_amdgcn_rcpf(e0 + 1.0f);
        float h1 = 1.0f - 2.0f * __builtin_amdgcn_rcpf(e1 + 1.0f);
        float h2 = 1.0f - 2.0f * __builtin_amdgcn_rcpf(e2 + 1.0f);
        float h3 = 1.0f - 2.0f * __builtin_amdgcn_rcpf(e3 + 1.0f);

        if (g == 0) {   // one writer per unit quad (2-way bank alias: free)
            *(float4*)(hbuf + (cur ^ 1) * HP + (u0 >> 4) * CS + (u0 & 15)) =
                make_float4(h0, h1, h2, h3);
        }
        cur ^= 1;
        __syncthreads();                                       // one barrier/step
    }

    // fc on final hidden state
    if (tid < V_) {
        float acc = b_fc[tid];
        const float*  hf = hbuf + cur * HP;
        const float4* wf = (const float4*)(W_fc + tid * H_);
        #pragma unroll
        for (int c = 0; c < NCH; ++c) {
            #pragma unroll
            for (int k = 0; k < 4; ++k) {
                float4 h4 = *(const float4*)(hf + c * CS + 4 * k);
                float4 w4 = wf[c * 4 + k];
                acc = fmaf(h4.x, w4.x, acc); acc = fmaf(h4.y, w4.y, acc);
                acc = fmaf(h4.z, w4.z, acc); acc = fmaf(h4.w, w4.w, acc);
            }
        }
        out[b * V_ + tid] = acc;
    }
}

extern "C" void kernel_launch(void* const* d_in, const int* in_sizes, int n_in,
                              void* d_out, int out_size, void* d_ws, size_t ws_size,
                              hipStream_t stream)
{
    const float* x    = (const float*)d_in[0];
    const float* W_ih = (const float*)d_in[1];
    const float* b_ih = (const float*)d_in[2];
    const float* W_hh = (const float*)d_in[3];
    const float* b_hh = (const float*)d_in[4];
    const float* W_fc = (const float*)d_in[5];
    const float* b_fc = (const float*)d_in[6];
    float* out = (float*)d_out;
    int*   idx = (int*)d_ws;  // B_*T_ ints = 1 MiB scratch

    const int n4 = (B_ * T_ * V_) / 4;
    hipLaunchKernelGGL(onehot_idx_kernel, dim3(2048), dim3(256), 0, stream,
                       (const float4*)x, n4, idx);
    hipLaunchKernelGGL(rnn_kernel, dim3(B_), dim3(TPB), 0, stream,
                       W_ih, b_ih, W_hh, b_hh, W_fc, b_fc, idx, out);
}

// Round 7
// 273.916 us; speedup vs baseline: 1.1763x; 1.0037x over previous
//
#include <hip/hip_runtime.h>

#define B_ 512
#define T_ 512
#define V_ 96
#define H_ 128
#define K2F 2.8853900817779268f   // 2*log2(e): exp(2s) == exp2(K2F*s)

typedef _Float16 h2_t __attribute__((ext_vector_type(2)));

__device__ __forceinline__ h2_t as_h2(unsigned u) {
    union { unsigned u; h2_t h; } v; v.u = u; return v.h;
}
__device__ __forceinline__ unsigned as_u32(h2_t h) {
    union { h2_t h; unsigned u; } v; v.h = h; return v.u;
}
// v_cvt_pkrtz_f16_f32: pack 2 fp32 -> 2 fp16 (RTZ), return raw dword
__device__ __forceinline__ unsigned pkrtz_u32(float a, float b) {
    auto r = __builtin_amdgcn_cvt_pkrtz(a, b);
    union { decltype(r) h; unsigned u; } v; v.h = r; return v.u;
}
__device__ __forceinline__ float fdot2(h2_t a, h2_t b, float c) {
#if __has_builtin(__builtin_amdgcn_fdot2)
    return __builtin_amdgcn_fdot2(a, b, c, false);
#else
    return fmaf((float)a.x, (float)b.x, fmaf((float)a.y, (float)b.y, c));
#endif
}
template<int CTRL>
__device__ __forceinline__ float dpp_add(float x) {
    int y = __builtin_amdgcn_update_dpp(0, __float_as_int(x), CTRL, 0xF, 0xF, true);
    return x + __int_as_float(y);
}

// Pass 1a: recover the one-hot index per (b,t). x is exactly {0.0, 1.0}.
__global__ __launch_bounds__(256) void onehot_idx_kernel(
    const float4* __restrict__ x4, int n4, int* __restrict__ idx)
{
    int stride = gridDim.x * blockDim.x;
    for (int e4 = blockIdx.x * blockDim.x + threadIdx.x; e4 < n4; e4 += stride) {
        float4 v = x4[e4];
        int base = e4 * 4;
        if (v.x > 0.5f) idx[(base + 0) / V_] = (base + 0) % V_;
        if (v.y > 0.5f) idx[(base + 1) / V_] = (base + 1) % V_;
        if (v.z > 0.5f) idx[(base + 2) / V_] = (base + 2) % V_;
        if (v.w > 0.5f) idx[(base + 3) / V_] = (base + 3) % V_;
    }
}

// Pass 1b: xwT[v][h] = (W_ih[h][v] + b_ih[h] + b_hh[h]) * K2F  (fp32, global)
__global__ __launch_bounds__(256) void build_xwT_kernel(
    const float* __restrict__ W_ih, const float* __restrict__ b_ih,
    const float* __restrict__ b_hh, float* __restrict__ xwT)
{
    int e = blockIdx.x * blockDim.x + threadIdx.x;
    if (e < V_ * H_) {
        int v = e >> 7, h = e & 127;
        xwT[e] = (W_ih[h * V_ + v] + b_ih[h] + b_hh[h]) * K2F;
    }
}

// Pass 1c: pack W_hh into per-lane fp16 dwords (RNE casts).
// Load layout in rnn_wave: uint4 w4[r4] = whh2_u4[r4*64 + lane]
//   -> dword D = r4*256 + lane*4 + j ; reg r = 4*r4+j ; m = r>>5 ; p = r&31
//   value = pack(W_hh[4*(l>>1)+m][64*(l&1)+2p], next k)
__global__ __launch_bounds__(256) void build_whh2_kernel(
    const float* __restrict__ W_hh, unsigned* __restrict__ whh2)
{
    int D = blockIdx.x * blockDim.x + threadIdx.x;
    if (D < 64 * H_) {
        int r4  = D >> 8;
        int rem = D & 255;
        int l   = rem >> 2;
        int j   = rem & 3;
        int r   = (r4 << 2) + j;
        int m   = r >> 5;
        int p   = r & 31;
        int unit = ((l >> 1) << 2) + m;
        int k    = ((l & 1) << 6) + (p << 1);
        h2_t pk;
        pk.x = (_Float16)W_hh[unit * H_ + k];
        pk.y = (_Float16)W_hh[unit * H_ + k + 1];
        whh2[D] = as_u32(pk);
    }
}

// Pass 2: ONE WAVE per batch row -- no barriers anywhere in the step loop.
// lane = (ug = l>>1 -> units 4*ug..4*ug+3,  c = l&1 -> K-half [64c,64c+64)).
// Weights: 128 packed-fp16 VGPRs. h: fp16 in LDS (broadcast reads, 2-way
// bank alias = free). K-reduce: single DPP xor1. xw gather: GLOBAL
// (L2-resident), prefetched one step ahead (no barrier -> no vmcnt drain).
__global__ __launch_bounds__(64) void rnn_wave_kernel(
    const uint4* __restrict__ whh2, const float* __restrict__ xwT,
    const int*  __restrict__ idx,
    const float* __restrict__ W_fc, const float* __restrict__ b_fc,
    float* __restrict__ out)
{
    const int b  = blockIdx.x;
    const int l  = threadIdx.x;      // 0..63
    const int c  = l & 1;            // K-half
    const int u0 = (l >> 1) << 2;    // first of this lane's 4 units

    __shared__ int      idx_s[T_];
    __shared__ _Float16 hbuf[2][H_];

    for (int e = l; e < T_; e += 64) idx_s[e] = idx[b * T_ + e];
    hbuf[0][l]      = (_Float16)0.f;
    hbuf[0][l + 64] = (_Float16)0.f;

    uint4 w4[32];
    #pragma unroll
    for (int r4 = 0; r4 < 32; ++r4) w4[r4] = whh2[r4 * 64 + l];

    int cur = 0;
    float4 xw = *(const float4*)(xwT + idx_s[0] * H_ + u0);

    for (int t = 0; t < T_; ++t) {
        // prefetch next step's gather: global load, ~1 full step of slack
        const int idn = idx_s[(t + 1) & (T_ - 1)];
        const float4 xwn = *(const float4*)(xwT + idn * H_ + u0);

        // this lane's K-half of h: 8 broadcast b128 reads
        const uint4* hp = (const uint4*)((const char*)&hbuf[cur][0] + (c << 7));
        uint4 h4[8];
        #pragma unroll
        for (int i = 0; i < 8; ++i) h4[i] = hp[i];

        float a0 = 0.f, a1 = 0.f, a2 = 0.f, a3 = 0.f;
        #pragma unroll
        for (int p4 = 0; p4 < 8; ++p4) {
            const unsigned hx[4] = {h4[p4].x, h4[p4].y, h4[p4].z, h4[p4].w};
            const unsigned wx0[4] = {w4[ 0+p4].x, w4[ 0+p4].y, w4[ 0+p4].z, w4[ 0+p4].w};
            const unsigned wx1[4] = {w4[ 8+p4].x, w4[ 8+p4].y, w4[ 8+p4].z, w4[ 8+p4].w};
            const unsigned wx2[4] = {w4[16+p4].x, w4[16+p4].y, w4[16+p4].z, w4[16+p4].w};
            const unsigned wx3[4] = {w4[24+p4].x, w4[24+p4].y, w4[24+p4].z, w4[24+p4].w};
            #pragma unroll
            for (int j = 0; j < 4; ++j) {
                const h2_t hh = as_h2(hx[j]);
                a0 = fdot2(hh, as_h2(wx0[j]), a0);
                a1 = fdot2(hh, as_h2(wx1[j]), a1);
                a2 = fdot2(hh, as_h2(wx2[j]), a2);
                a3 = fdot2(hh, as_h2(wx3[j]), a3);
            }
        }
        // add partner K-half (lane c^1): single DPP xor1 stage
        a0 = dpp_add<0xB1>(a0); a1 = dpp_add<0xB1>(a1);
        a2 = dpp_add<0xB1>(a2); a3 = dpp_add<0xB1>(a3);

        // tanh(s) = 1 - 2/(exp2(K2F*s + xw) + 1)   (fp32)
        float e0 = __builtin_amdgcn_exp2f(fmaf(a0, K2F, xw.x));
        float e1 = __builtin_amdgcn_exp2f(fmaf(a1, K2F, xw.y));
        float e2 = __builtin_amdgcn_exp2f(fmaf(a2, K2F, xw.z));
        float e3 = __builtin_amdgcn_exp2f(fmaf(a3, K2F, xw.w));
        float h0 = 1.0f - 2.0f * __builtin_amdgcn_rcpf(e0 + 1.0f);
        float h1 = 1.0f - 2.0f * __builtin_amdgcn_rcpf(e1 + 1.0f);
        float h2v = 1.0f - 2.0f * __builtin_amdgcn_rcpf(e2 + 1.0f);
        float h3 = 1.0f - 2.0f * __builtin_amdgcn_rcpf(e3 + 1.0f);

        if (c == 0) {                         // 32 lanes write 8B each (2-way: free)
            *(uint2*)((char*)&hbuf[cur ^ 1][0] + (u0 << 1)) =
                make_uint2(pkrtz_u32(h0, h1), pkrtz_u32(h2v, h3));
        }
        cur ^= 1;
        xw = xwn;
    }

    // fc on final hidden state (one-time; scalar LDS reads are fine here)
    for (int v = l; v < V_; v += 64) {
        float acc = b_fc[v];
        const float4* wf = (const float4*)(W_fc + v * H_);
        #pragma unroll 8
        for (int k4 = 0; k4 < 32; ++k4) {
            float4 wv = wf[k4];
            acc = fmaf((float)hbuf[cur][4 * k4 + 0], wv.x, acc);
            acc = fmaf((float)hbuf[cur][4 * k4 + 1], wv.y, acc);
            acc = fmaf((float)hbuf[cur][4 * k4 + 2], wv.z, acc);
            acc = fmaf((float)hbuf[cur][4 * k4 + 3], wv.w, acc);
        }
        out[b * V_ + v] = acc;
    }
}

extern "C" void kernel_launch(void* const* d_in, const int* in_sizes, int n_in,
                              void* d_out, int out_size, void* d_ws, size_t ws_size,
                              hipStream_t stream)
{
    const float* x    = (const float*)d_in[0];
    const float* W_ih = (const float*)d_in[1];
    const float* b_ih = (const float*)d_in[2];
    const float* W_hh = (const float*)d_in[3];
    const float* b_hh = (const float*)d_in[4];
    const float* W_fc = (const float*)d_in[5];
    const float* b_fc = (const float*)d_in[6];
    float* out = (float*)d_out;

    int*      idx  = (int*)d_ws;                                    // 1 MiB
    float*    xwT  = (float*)((char*)d_ws + (size_t)B_ * T_ * 4);   // 48 KiB
    unsigned* whh2 = (unsigned*)((char*)xwT + (size_t)V_ * H_ * 4); // 32 KiB

    const int n4 = (B_ * T_ * V_) / 4;
    hipLaunchKernelGGL(onehot_idx_kernel, dim3(2048), dim3(256), 0, stream,
                       (const float4*)x, n4, idx);
    hipLaunchKernelGGL(build_xwT_kernel, dim3((V_ * H_ + 255) / 256), dim3(256),
                       0, stream, W_ih, b_ih, b_hh, xwT);
    hipLaunchKernelGGL(build_whh2_kernel, dim3((64 * H_ + 255) / 256), dim3(256),
                       0, stream, W_hh, whh2);
    hipLaunchKernelGGL(rnn_wave_kernel, dim3(B_), dim3(64), 0, stream,
                       (const uint4*)whh2, xwT, idx, W_fc, b_fc, out);
}